// Round 5
// baseline (139.940 us; speedup 1.0000x reference)
//
#include <hip/hip_runtime.h>

#define NB 128      // batch
#define NT 4096     // T
#define DKD 16      // d_k == d_q
#define DW 32       // d_w
#define BLK 1024    // 16 waves/block, one block per batch -> no cross-block sync
#define PT 4        // t-values per thread: NT / BLK

__device__ __forceinline__ float fast_tanh(float x) {
    // tanh(x) = 1 - 2/(e^{2x}+1); exact at +/-inf limits, ~1 ulp rcp error.
    float e = __expf(2.0f * x);
    return 1.0f - 2.0f * __builtin_amdgcn_rcpf(e + 1.0f);
}

// Fully fused additive attention: ONE kernel, one block per batch row.
// p = exp(score) needs no max-subtract (|score| <= ||v_w||_1+|v_b| ~ 2.6
// since tanh is bounded). Block computes all 4096 p's (kept in registers),
// block-reduces L = sum(p) and ctx = sum(p*value), then every thread
// normalizes its in-register p's and writes attn ONCE. No workspace, no
// second launch, no attn RMW round-trip.
__global__ __launch_bounds__(BLK, 1) void aa_fused(
    const float* __restrict__ query, const float* __restrict__ key,
    const float* __restrict__ value, const float* __restrict__ W1,
    const float* __restrict__ W2, const float* __restrict__ bias,
    const float* __restrict__ v_w, const float* __restrict__ v_b,
    float* __restrict__ out)       // [0,2048) context, [2048,...) attn
{
    const int b   = blockIdx.x;
    const int tid = threadIdx.x;

    __shared__ float s_comb[DW];        // q_proj[w] + bias (block-uniform)
    __shared__ float s_rl[16];          // per-wave partial l
    __shared__ float s_rctx[16 * 16];   // per-wave partial ctx

    // Preamble: 32 lanes compute comb[w] = q.W1[w] + bias.
    if (tid < DW) {
        const int w = tid;
        float acc = bias[0];
        const float* q  = query + b * DKD;
        const float* w1 = W1 + w * DKD;
        #pragma unroll
        for (int d = 0; d < DKD; ++d) acc = fmaf(q[d], w1[d], acc);
        s_comb[w] = acc;
    }
    __syncthreads();

    const float vb = v_b[0];
    // Thread handles PT=4 consecutive t's (t = tid*4+j): 256 B contiguous
    // per lane for key/value, coalesced float4 attn store at the end.
    const float4* kp = reinterpret_cast<const float4*>(key)   + ((size_t)b * NT + tid * PT) * 4;
    const float4* vp = reinterpret_cast<const float4*>(value) + ((size_t)b * NT + tid * PT) * 4;

    float p[PT];
    float l = 0.0f;
    float ctx[16];
    #pragma unroll
    for (int d = 0; d < 16; ++d) ctx[d] = 0.0f;

    #pragma unroll
    for (int j = 0; j < PT; ++j) {
        // 4 independent key float4 loads, immediately consumed by the w-loop.
        const float4 k0 = kp[4*j + 0], k1 = kp[4*j + 1];
        const float4 k2 = kp[4*j + 2], k3 = kp[4*j + 3];

        float sc = vb;
        // Fully unrolled w-loop: W2[w*16+d] / v_w[w] are wave-uniform
        // constant indices -> scalar loads on the SMEM/constant-cache pipe,
        // co-issued with VALU; comb[w] is an LDS broadcast.
        #pragma unroll
        for (int w = 0; w < DW; ++w) {
            const float* wr = W2 + w * DKD;
            float h = s_comb[w];
            h = fmaf(k0.x, wr[ 0], h); h = fmaf(k0.y, wr[ 1], h);
            h = fmaf(k0.z, wr[ 2], h); h = fmaf(k0.w, wr[ 3], h);
            h = fmaf(k1.x, wr[ 4], h); h = fmaf(k1.y, wr[ 5], h);
            h = fmaf(k1.z, wr[ 6], h); h = fmaf(k1.w, wr[ 7], h);
            h = fmaf(k2.x, wr[ 8], h); h = fmaf(k2.y, wr[ 9], h);
            h = fmaf(k2.z, wr[10], h); h = fmaf(k2.w, wr[11], h);
            h = fmaf(k3.x, wr[12], h); h = fmaf(k3.y, wr[13], h);
            h = fmaf(k3.z, wr[14], h); h = fmaf(k3.w, wr[15], h);
            sc = fmaf(fast_tanh(h), v_w[w], sc);
        }
        p[j] = __expf(sc);
        l += p[j];

        // 4 independent value float4 loads, immediately consumed.
        const float4 v0 = vp[4*j + 0], v1 = vp[4*j + 1];
        const float4 v2 = vp[4*j + 2], v3 = vp[4*j + 3];
        ctx[ 0] = fmaf(p[j], v0.x, ctx[ 0]); ctx[ 1] = fmaf(p[j], v0.y, ctx[ 1]);
        ctx[ 2] = fmaf(p[j], v0.z, ctx[ 2]); ctx[ 3] = fmaf(p[j], v0.w, ctx[ 3]);
        ctx[ 4] = fmaf(p[j], v1.x, ctx[ 4]); ctx[ 5] = fmaf(p[j], v1.y, ctx[ 5]);
        ctx[ 6] = fmaf(p[j], v1.z, ctx[ 6]); ctx[ 7] = fmaf(p[j], v1.w, ctx[ 7]);
        ctx[ 8] = fmaf(p[j], v2.x, ctx[ 8]); ctx[ 9] = fmaf(p[j], v2.y, ctx[ 9]);
        ctx[10] = fmaf(p[j], v2.z, ctx[10]); ctx[11] = fmaf(p[j], v2.w, ctx[11]);
        ctx[12] = fmaf(p[j], v3.x, ctx[12]); ctx[13] = fmaf(p[j], v3.y, ctx[13]);
        ctx[14] = fmaf(p[j], v3.z, ctx[14]); ctx[15] = fmaf(p[j], v3.w, ctx[15]);
    }

    // Block reduction: wave shuffle-reduce, then 16 waves via LDS.
    #pragma unroll
    for (int o = 32; o > 0; o >>= 1) l += __shfl_xor(l, o);
    #pragma unroll
    for (int d = 0; d < 16; ++d) {
        #pragma unroll
        for (int o = 32; o > 0; o >>= 1) ctx[d] += __shfl_xor(ctx[d], o);
    }
    const int wave = tid >> 6;
    const int lane = tid & 63;
    if (lane == 0) {
        s_rl[wave] = l;
        #pragma unroll
        for (int d = 0; d < 16; ++d) s_rctx[wave * 16 + d] = ctx[d];
    }
    __syncthreads();

    // Every thread forms L from the 16 wave partials (LDS broadcast reads).
    float L = 0.0f;
    #pragma unroll
    for (int w = 0; w < 16; ++w) L += s_rl[w];
    const float inv = 1.0f / L;

    // Single normalized attn write: coalesced float4 per thread.
    reinterpret_cast<float4*>(out + NB * DKD + (size_t)b * NT)[tid] =
        make_float4(p[0] * inv, p[1] * inv, p[2] * inv, p[3] * inv);

    if (tid < DKD) {
        float s = 0.0f;
        #pragma unroll
        for (int w = 0; w < 16; ++w) s += s_rctx[w * 16 + tid];
        out[b * DKD + tid] = s * inv;
    }
}

extern "C" void kernel_launch(void* const* d_in, const int* in_sizes, int n_in,
                              void* d_out, int out_size, void* d_ws, size_t ws_size,
                              hipStream_t stream) {
    const float* query = (const float*)d_in[0];
    const float* key   = (const float*)d_in[1];
    const float* value = (const float*)d_in[2];
    const float* W1    = (const float*)d_in[3];
    const float* W2    = (const float*)d_in[4];
    const float* bias  = (const float*)d_in[5];
    const float* v_w   = (const float*)d_in[6];
    const float* v_b   = (const float*)d_in[7];
    float* out = (float*)d_out;

    aa_fused<<<NB, BLK, 0, stream>>>(query, key, value, W1, W2, bias,
                                     v_w, v_b, out);
}

// Round 6
// 121.697 us; speedup vs baseline: 1.1499x; 1.1499x over previous
//
#include <hip/hip_runtime.h>

#define NB 128      // batch
#define NT 4096     // T
#define DKD 16      // d_k == d_q
#define DW 32       // d_w
#define CHUNKS 8    // 1024 blocks = 4 blocks/CU = 16 waves/CU
#define TC 512      // NT / CHUNKS
#define BLK 256
#define PT 2        // t-values per thread
#define BLK2 128    // finish kernel block

__device__ __forceinline__ float fast_tanh(float x) {
    // tanh(x) = 1 - 2/(e^{2x}+1); exact at +/-inf limits, ~1 ulp rcp error.
    float e = __expf(2.0f * x);
    return 1.0f - 2.0f * __builtin_amdgcn_rcpf(e + 1.0f);
}

// R6: same math as R3, but the w-loop is ROLLED (#pragma unroll 1).
// Theory: R1-R5 fully unrolled it -> 24-48 KB straight-line bodies that
// thrash the I$; every pipe idle, perf insensitive to occupancy/data-path.
// Rolled body ~350 B stays I$-resident. W2 row read via wave-uniform
// s_load (SMEM pipe) inside the loop; comb/v_w packed as one ds_read_b64.
__global__ __launch_bounds__(BLK, 4) void aa_score(
    const float* __restrict__ query, const float* __restrict__ key,
    const float* __restrict__ value, const float* __restrict__ W1,
    const float* __restrict__ W2, const float* __restrict__ bias,
    const float* __restrict__ v_w, const float* __restrict__ v_b,
    float* __restrict__ attn,      // d_out + 2048
    float* __restrict__ ws_l,      // [NB*CHUNKS]
    float* __restrict__ ws_ctx)    // [NB*CHUNKS*16]
{
    const int b   = blockIdx.x >> 3;   // / CHUNKS
    const int c   = blockIdx.x & 7;    // % CHUNKS
    const int tid = threadIdx.x;

    __shared__ float s_cv[2 * DW];     // interleaved {comb[w], v_w[w]}
    __shared__ float s_rctx[4 * 16];   // per-wave partial ctx
    __shared__ float s_rl[4];

    // Issue this thread's 8 independent key float4 loads first.
    const size_t tbase = (size_t)b * NT + (size_t)c * TC + (size_t)tid * PT;
    const float4* kp = reinterpret_cast<const float4*>(key)   + tbase * 4;
    const float4* vp = reinterpret_cast<const float4*>(value) + tbase * 4;
    float4 ka[8];
    #pragma unroll
    for (int r = 0; r < 8; ++r) ka[r] = kp[r];

    // Preamble: 32 lanes compute comb[w] = q.W1[w] + bias; pack with v_w.
    if (tid < DW) {
        const int w = tid;
        float acc = bias[0];
        const float* q  = query + b * DKD;
        const float* w1 = W1 + w * DKD;
        #pragma unroll
        for (int d = 0; d < DKD; ++d) acc = fmaf(q[d], w1[d], acc);
        s_cv[2 * w]     = acc;
        s_cv[2 * w + 1] = v_w[w];
    }
    __syncthreads();

    const float vb = v_b[0];
    float sc0 = vb, sc1 = vb;

    // ROLLED w-loop: ~50 instrs/iter. wr[] has a loop-variant but
    // wave-uniform address -> scalar loads; cv is one ds_read_b64.
    #pragma unroll 1
    for (int w = 0; w < DW; ++w) {
        const float* wr = W2 + (w << 4);
        const float2 cv = *reinterpret_cast<const float2*>(s_cv + 2 * w);
        float h0 = cv.x, h1 = cv.x;
        h0 = fmaf(ka[0].x, wr[ 0], h0); h0 = fmaf(ka[0].y, wr[ 1], h0);
        h0 = fmaf(ka[0].z, wr[ 2], h0); h0 = fmaf(ka[0].w, wr[ 3], h0);
        h0 = fmaf(ka[1].x, wr[ 4], h0); h0 = fmaf(ka[1].y, wr[ 5], h0);
        h0 = fmaf(ka[1].z, wr[ 6], h0); h0 = fmaf(ka[1].w, wr[ 7], h0);
        h0 = fmaf(ka[2].x, wr[ 8], h0); h0 = fmaf(ka[2].y, wr[ 9], h0);
        h0 = fmaf(ka[2].z, wr[10], h0); h0 = fmaf(ka[2].w, wr[11], h0);
        h0 = fmaf(ka[3].x, wr[12], h0); h0 = fmaf(ka[3].y, wr[13], h0);
        h0 = fmaf(ka[3].z, wr[14], h0); h0 = fmaf(ka[3].w, wr[15], h0);
        h1 = fmaf(ka[4].x, wr[ 0], h1); h1 = fmaf(ka[4].y, wr[ 1], h1);
        h1 = fmaf(ka[4].z, wr[ 2], h1); h1 = fmaf(ka[4].w, wr[ 3], h1);
        h1 = fmaf(ka[5].x, wr[ 4], h1); h1 = fmaf(ka[5].y, wr[ 5], h1);
        h1 = fmaf(ka[5].z, wr[ 6], h1); h1 = fmaf(ka[5].w, wr[ 7], h1);
        h1 = fmaf(ka[6].x, wr[ 8], h1); h1 = fmaf(ka[6].y, wr[ 9], h1);
        h1 = fmaf(ka[6].z, wr[10], h1); h1 = fmaf(ka[6].w, wr[11], h1);
        h1 = fmaf(ka[7].x, wr[12], h1); h1 = fmaf(ka[7].y, wr[13], h1);
        h1 = fmaf(ka[7].z, wr[14], h1); h1 = fmaf(ka[7].w, wr[15], h1);
        sc0 = fmaf(fast_tanh(h0), cv.y, sc0);
        sc1 = fmaf(fast_tanh(h1), cv.y, sc1);
    }

    const float p0 = __expf(sc0);
    const float p1 = __expf(sc1);
    reinterpret_cast<float2*>(attn + (size_t)b * NT + (size_t)c * TC)[tid] =
        make_float2(p0, p1);

    // 8 independent value float4 loads, immediately consumed.
    float ctx[16];
    {
        const float4 v0 = vp[0], v1 = vp[1], v2 = vp[2], v3 = vp[3];
        const float4 v4 = vp[4], v5 = vp[5], v6 = vp[6], v7 = vp[7];
        ctx[ 0] = fmaf(p1, v4.x, p0 * v0.x); ctx[ 1] = fmaf(p1, v4.y, p0 * v0.y);
        ctx[ 2] = fmaf(p1, v4.z, p0 * v0.z); ctx[ 3] = fmaf(p1, v4.w, p0 * v0.w);
        ctx[ 4] = fmaf(p1, v5.x, p0 * v1.x); ctx[ 5] = fmaf(p1, v5.y, p0 * v1.y);
        ctx[ 6] = fmaf(p1, v5.z, p0 * v1.z); ctx[ 7] = fmaf(p1, v5.w, p0 * v1.w);
        ctx[ 8] = fmaf(p1, v6.x, p0 * v2.x); ctx[ 9] = fmaf(p1, v6.y, p0 * v2.y);
        ctx[10] = fmaf(p1, v6.z, p0 * v2.z); ctx[11] = fmaf(p1, v6.w, p0 * v2.w);
        ctx[12] = fmaf(p1, v7.x, p0 * v3.x); ctx[13] = fmaf(p1, v7.y, p0 * v3.y);
        ctx[14] = fmaf(p1, v7.z, p0 * v3.z); ctx[15] = fmaf(p1, v7.w, p0 * v3.w);
    }

    // Block reduction: wave shuffle-reduce, then 4 waves via LDS.
    float l = p0 + p1;
    #pragma unroll
    for (int o = 32; o > 0; o >>= 1) l += __shfl_xor(l, o);
    #pragma unroll 1
    for (int d = 0; d < 16; ++d) {
        float v = ctx[d];
        #pragma unroll
        for (int o = 32; o > 0; o >>= 1) v += __shfl_xor(v, o);
        ctx[d] = v;
    }
    const int wave = tid >> 6;
    const int lane = tid & 63;
    if (lane == 0) {
        s_rl[wave] = l;
        #pragma unroll 1
        for (int d = 0; d < 16; ++d) s_rctx[wave * 16 + d] = ctx[d];
    }
    __syncthreads();
    const int slot = b * CHUNKS + c;
    if (tid < 16)
        ws_ctx[slot * 16 + tid] =
            s_rctx[tid] + s_rctx[16 + tid] + s_rctx[32 + tid] + s_rctx[48 + tid];
    if (tid == 0)
        ws_l[slot] = s_rl[0] + s_rl[1] + s_rl[2] + s_rl[3];
}

// Kernel 2: normalize attn in place by 1/L and write context.
__global__ __launch_bounds__(BLK2) void aa_finish(
    float* __restrict__ out,          // [0,2048) context, [2048,...) attn
    const float* __restrict__ ws_l,
    const float* __restrict__ ws_ctx)
{
    const int b   = blockIdx.x >> 3;
    const int seg = blockIdx.x & 7;
    const int tid = threadIdx.x;
    float L = 0.0f;
    #pragma unroll
    for (int i = 0; i < CHUNKS; ++i) L += ws_l[b * CHUNKS + i];
    const float inv = 1.0f / L;

    float4* ap = reinterpret_cast<float4*>(out + NB*DKD + (size_t)b * NT + (size_t)seg * 512);
    float4 p = ap[tid];
    p.x *= inv; p.y *= inv; p.z *= inv; p.w *= inv;
    ap[tid] = p;

    if (seg == 0 && tid < DKD) {
        const float* wc = ws_ctx + b * CHUNKS * 16;
        float s = 0.0f;
        #pragma unroll
        for (int i = 0; i < CHUNKS; ++i) s += wc[i * 16 + tid];
        out[b * DKD + tid] = s * inv;
    }
}

extern "C" void kernel_launch(void* const* d_in, const int* in_sizes, int n_in,
                              void* d_out, int out_size, void* d_ws, size_t ws_size,
                              hipStream_t stream) {
    const float* query = (const float*)d_in[0];
    const float* key   = (const float*)d_in[1];
    const float* value = (const float*)d_in[2];
    const float* W1    = (const float*)d_in[3];
    const float* W2    = (const float*)d_in[4];
    const float* bias  = (const float*)d_in[5];
    const float* v_w   = (const float*)d_in[6];
    const float* v_b   = (const float*)d_in[7];
    float* out = (float*)d_out;

    float* ws_l   = (float*)d_ws;          // NB*CHUNKS floats
    float* ws_ctx = ws_l + NB * CHUNKS;    // NB*CHUNKS*16 floats

    aa_score<<<NB * CHUNKS, BLK, 0, stream>>>(
        query, key, value, W1, W2, bias, v_w, v_b,
        out + NB * DKD, ws_l, ws_ctx);
    aa_finish<<<NB * 8, BLK2, 0, stream>>>(out, ws_l, ws_ctx);
}